// Round 4
// baseline (450.667 us; speedup 1.0000x reference)
//
#include <hip/hip_runtime.h>

// VQ-VAE forward: x [64,64,32,32] f32 (NCHW, C==D), weight [512,64] f32.
// d_out: loss (1) | q_out (4194304, NCHW) | encodings (33554432, [N,K]).
//
// R4: invert operand roles. lane<->code: each lane holds its codebook row in
// 64 VGPRs (loaded once; w scalar traffic eliminated). x row is the
// wave-uniform operand: 64 s_load_dword (imm offsets off one readfirstlane'd
// base), 16 MB total vs R3's 128 MB scalar-path traffic. Argmin = in-wave
// shfl min + ballot lowest-lane (== lowest k), cross-wave ascending strict <.
// Per-(r,k) dist arithmetic bit-identical to R3 (fmaf pairs == pk_fma lanes).

#define NROWS 65536
#define DIM 64
#define KCODES 512
#define HW 1024
#define TPB 512                     // 8 waves: wave wv owns codes [64wv,64wv+64)
#define RPB 128                     // rows per block
#define NBLOCKS (NROWS / RPB)       // 512
#define NW 8

typedef float v2f __attribute__((ext_vector_type(2)));
typedef float v4f __attribute__((ext_vector_type(4)));

__global__ __launch_bounds__(TPB, 4) void vq_main(
    const float* __restrict__ x,
    const float* __restrict__ w,
    float* __restrict__ out,
    float* __restrict__ partial)
{
    __shared__ float x2s[RPB];
    __shared__ float bd[RPB][NW];
    __shared__ int   bk[RPB][NW];
    __shared__ int   idxf[RPB];
    __shared__ float lred[NW];

    const int t    = threadIdx.x;
    const int lane = t & 63;
    const int wv   = __builtin_amdgcn_readfirstlane(t >> 6);
    const int n0   = blockIdx.x * RPB;
    const int b    = n0 >> 10;        // 1024 % 128 == 0: no b straddle
    const int hw0  = n0 & 1023;

    // ---- per-lane codebook row -> VGPRs (once). kcode ascending in (wv,lane).
    const int kcode = wv * 64 + lane;
    v2f wreg[DIM / 2];
    {
        const v4f* wr4 = (const v4f*)(w + kcode * DIM);
        #pragma unroll
        for (int i = 0; i < DIM / 4; ++i) {
            const v4f tmp = wr4[i];
            wreg[2 * i]     = (v2f){tmp[0], tmp[1]};
            wreg[2 * i + 1] = (v2f){tmp[2], tmp[3]};
        }
    }
    // e2 for this lane's code: ascending d, mul-then-add (same as R1-R3).
    float e2l = 0.0f;
    #pragma unroll
    for (int i = 0; i < DIM / 2; ++i) {
        e2l = __fadd_rn(e2l, __fmul_rn(wreg[i][0], wreg[i][0]));
        e2l = __fadd_rn(e2l, __fmul_rn(wreg[i][1], wreg[i][1]));
    }

    // ---- x2 per row (threads 0..127; per-lane row; coalesced per d).
    if (t < RPB) {
        const float* xr = x + (size_t)b * DIM * HW + hw0 + t;
        float s = 0.0f;
        #pragma unroll
        for (int d = 0; d < DIM; ++d) {
            const float xd = xr[(size_t)d * HW];
            s = __fadd_rn(s, __fmul_rn(xd, xd));
        }
        x2s[t] = s;
    }
    __syncthreads();

    // ---- main loop: per row, dist for this lane's code; x via scalar loads.
    const int xbase = b * DIM * HW + hw0;     // fits 32-bit (x = 4.19M floats)
    #pragma unroll 1
    for (int r = 0; r < RPB; ++r) {
        // force-uniform base so x loads become s_load with imm offsets
        const int rb = __builtin_amdgcn_readfirstlane(xbase + r);
        float a0 = 0.0f, a1 = 0.0f;
        #pragma unroll
        for (int i = 0; i < DIM / 2; ++i) {
            const float xa = x[rb + (2 * i) * HW];        // s_load_dword
            const float xb = x[rb + (2 * i + 1) * HW];    // s_load_dword
            a0 = __builtin_fmaf(xa, wreg[i][0], a0);      // == pk_fma lane 0
            a1 = __builtin_fmaf(xb, wreg[i][1], a1);      // == pk_fma lane 1
        }
        const float dot  = a0 + a1;                       // same as a[0]+a[1]
        const float dist = __fsub_rn(__fadd_rn(x2s[r], e2l),
                                     __fmul_rn(2.0f, dot));

        // in-wave min (value), then lowest tied lane = lowest k (first-min)
        float m = dist;
        #pragma unroll
        for (int off = 32; off; off >>= 1) {
            const float o = __shfl_down(m, off, 64);
            m = (o < m) ? o : m;
        }
        const float mb = __int_as_float(
            __builtin_amdgcn_readfirstlane(__float_as_int(m)));
        const unsigned long long eq = __ballot(dist == mb);
        if (lane == 0) {
            bd[r][wv] = mb;
            bk[r][wv] = wv * 64 + (int)__builtin_ctzll(eq);
        }
    }
    __syncthreads();

    // ---- cross-wave argmin: ascending wave (= ascending k), strict <.
    if (t < RPB) {
        float bb = bd[t][0];
        int   bi = bk[t][0];
        #pragma unroll
        for (int v = 1; v < NW; ++v) {
            const float c = bd[t][v];
            if (c < bb) { bb = c; bi = bk[t][v]; }
        }
        idxf[t] = bi;
    }
    __syncthreads();

    // ---- epilogue: q gather/store + loss. thread = (row rt, d-group dg).
    const int rt = t & (RPB - 1);
    const int dg = t >> 7;                   // 0..3 -> 16 d's each
    const int widx = idxf[rt];
    const float* wrow = w + widx * DIM + dg * 16;
    const float* xrow = x + (size_t)b * DIM * HW + hw0 + rt;
    float* q = out + 1;
    float lsum = 0.0f;
    #pragma unroll
    for (int j = 0; j < 16; ++j) {
        const int d = dg * 16 + j;
        const float wvv = wrow[j];           // per-lane gather, L1-hot
        const float xd  = xrow[(size_t)d * HW];
        const float df  = __fsub_rn(wvv, xd);
        lsum = __fadd_rn(lsum, __fmul_rn(df, df));
        q[(size_t)(b * DIM + d) * HW + hw0 + rt] = wvv;   // coalesced per d
    }

    #pragma unroll
    for (int off = 32; off; off >>= 1) lsum += __shfl_down(lsum, off, 64);
    if (lane == 0) lred[wv] = lsum;
    __syncthreads();
    if (t == 0) {
        float s = 0.0f;
        #pragma unroll
        for (int v = 0; v < NW; ++v) s += lred[v];
        partial[blockIdx.x] = s;
    }

    // ---- encodings: direct one-shot compute, aligned float4 middle
    // (slab global float index == 1 mod 4 -> peel 3, tail 1).
    float* slab = out + 1 + (size_t)NROWS * DIM + (size_t)n0 * KCODES;
    if (t < 3) slab[t] = (idxf[0] == t) ? 1.0f : 0.0f;
    if (t == 4) slab[RPB * KCODES - 1] = (idxf[RPB - 1] == 511) ? 1.0f : 0.0f;
    {
        v4f* s4 = (v4f*)(slab + 3);                 // 16B-aligned
        const int nf4 = (RPB * KCODES - 4) / 4;     // 16383
        for (int f = t; f < nf4; f += TPB) {        // lanes -> consecutive 16B
            const int ii = 3 + 4 * f;
            v4f o;
            #pragma unroll
            for (int c = 0; c < 4; ++c) {
                const int e = ii + c;
                o[c] = (idxf[e >> 9] == (e & 511)) ? 1.0f : 0.0f;
            }
            s4[f] = o;
        }
    }
}

__global__ __launch_bounds__(256) void vq_final(
    const float* __restrict__ partial, float* __restrict__ out)
{
    __shared__ float s[256];
    const int t = threadIdx.x;
    s[t] = partial[t] + partial[t + 256];
    __syncthreads();
    for (int off = 128; off; off >>= 1) {
        if (t < off) s[t] += s[t + off];
        __syncthreads();
    }
    if (t == 0) {
        const float m = s[0] / 4194304.0f;          // mean over B*H*W*D
        out[0] = __fadd_rn(m, __fmul_rn(0.25f, m)); // z_q + 0.25*z_e
    }
}

extern "C" void kernel_launch(void* const* d_in, const int* in_sizes, int n_in,
                              void* d_out, int out_size, void* d_ws, size_t ws_size,
                              hipStream_t stream) {
    const float* x = (const float*)d_in[0];
    const float* w = (const float*)d_in[1];
    float* out     = (float*)d_out;
    float* partial = (float*)d_ws;        // 512 floats of scratch

    vq_main<<<NBLOCKS, TPB, 0, stream>>>(x, w, out, partial);
    vq_final<<<1, 256, 0, stream>>>(partial, out);
}

// Round 6
// 282.295 us; speedup vs baseline: 1.5964x; 1.5964x over previous
//
#include <hip/hip_runtime.h>

// VQ-VAE forward: x [64,64,32,32] f32 (NCHW, C==D), weight [512,64] f32.
// d_out: loss (1) | q_out (4194304, NCHW) | encodings (33554432, [N,K]).
//
// R6 = R5 (register-tiled 4x4 outer-product GEMM) + tie-order fixes:
//  - contiguous per-lane k blocks (k0 = kbase + kg*32 + kit*4), so partition
//    order == index order (R5's stride-16 interleave broke first-min ties;
//    dists are ulp-quantized at ~7.6e-6 on a base of 64 -> exact ties exist)
//  - explicit lowest-index tie-break in both merge stages.
// Arithmetic chains identical to the passing rounds (even/odd fma chains,
// (x2+e2)-2dot, ascending scans).

#define NROWS 65536
#define DIM 64
#define KCODES 512
#define HW 1024
#define TPB 256
#define RPB 64                      // rows per block
#define NBLOCKS (NROWS / RPB)       // 1024
#define NW 4
#define KW (KCODES / NW)            // 128 codes per wave

// d_ws float offsets
#define WT_OFF 0                    // wT [64][512]    = 32768 floats
#define E2_OFF 32768                // e2 [512]
#define X2_OFF 33280                // x2 [65536]
#define PART_OFF 98816              // partials [1024]

typedef float v4f __attribute__((ext_vector_type(4)));

__global__ __launch_bounds__(256) void vq_prep(
    const float* __restrict__ x, const float* __restrict__ w,
    float* __restrict__ ws)
{
    const int bid = blockIdx.x, t = threadIdx.x;
    if (bid < 2) {
        // w transpose + e2 (ascending-d mul-then-add, same chain as R1-R4)
        const int k = bid * 256 + t;
        float s = 0.0f;
        for (int d = 0; d < DIM; ++d) {
            const float v = w[k * DIM + d];
            ws[WT_OFF + d * KCODES + k] = v;     // coalesced across k
            s = __fadd_rn(s, __fmul_rn(v, v));
        }
        ws[E2_OFF + k] = s;
    } else {
        // x2 per row, coalesced (lane = consecutive hw)
        const int n = (bid - 2) * 256 + t;
        const int b = n >> 10, hw = n & 1023;
        const float* xr = x + (size_t)b * DIM * HW + hw;
        float s = 0.0f;
        for (int d = 0; d < DIM; ++d) {
            const float v = xr[(size_t)d * HW];
            s = __fadd_rn(s, __fmul_rn(v, v));
        }
        ws[X2_OFF + n] = s;
    }
}

__global__ __launch_bounds__(TPB) void vq_main(
    const float* __restrict__ x, const float* __restrict__ w,
    const float* __restrict__ ws, float* __restrict__ out,
    float* __restrict__ partial)
{
    __shared__ float bestw[NW][RPB];
    __shared__ int   bidxw[NW][RPB];
    __shared__ int   idxf[RPB];
    __shared__ float lred[NW];

    const int t    = threadIdx.x;
    const int lane = t & 63;
    const int wv   = __builtin_amdgcn_readfirstlane(t >> 6);
    const int rg   = lane & 15;       // rows rg*4 .. rg*4+3
    const int kg   = lane >> 4;       // code block 0..3 (CONTIGUOUS 32 codes)
    const int n0   = blockIdx.x * RPB;
    const int b    = n0 >> 10;        // 1024 % 64 == 0: no b straddle
    const int hw0  = n0 & 1023;

    const float* wT = ws + WT_OFF;
    const float* e2 = ws + E2_OFF;

    const v4f x2r = *(const v4f*)(ws + X2_OFF + n0 + rg * 4);
    const float* xbase = x + (size_t)b * DIM * HW + hw0 + rg * 4;
    const int kbase = wv * KW + kg * 32;   // this lane's contiguous 32-code blk

    float best[4] = {3.4e38f, 3.4e38f, 3.4e38f, 3.4e38f};
    int   bidx[4] = {kbase, kbase, kbase, kbase};

    for (int kit = 0; kit < 8; ++kit) {              // 8 x 4 codes, ascending
        const int k0 = kbase + kit * 4;
        const v4f e4 = *(const v4f*)(e2 + k0);       // L1-hot
        v4f accE[4] = {{0,0,0,0},{0,0,0,0},{0,0,0,0},{0,0,0,0}};
        v4f accO[4] = {{0,0,0,0},{0,0,0,0},{0,0,0,0},{0,0,0,0}};
        const float* xp = xbase;
        const float* wp = wT + k0;
        #pragma unroll 8
        for (int dp = 0; dp < DIM / 2; ++dp) {       // 32 dual-d steps
            const v4f xE = *(const v4f*)(xp);        // rows, depth 2dp
            const v4f xO = *(const v4f*)(xp + HW);   // rows, depth 2dp+1
            const v4f wE = *(const v4f*)(wp);        // codes, depth 2dp
            const v4f wO = *(const v4f*)(wp + KCODES);
            #pragma unroll
            for (int r = 0; r < 4; ++r) {
                #pragma unroll
                for (int c = 0; c < 4; ++c) {
                    accE[r][c] = __builtin_fmaf(xE[r], wE[c], accE[r][c]);
                    accO[r][c] = __builtin_fmaf(xO[r], wO[c], accO[r][c]);
                }
            }
            xp += 2 * HW;
            wp += 2 * KCODES;
        }
        #pragma unroll
        for (int r = 0; r < 4; ++r) {
            #pragma unroll
            for (int c = 0; c < 4; ++c) {            // c ascending: first-min
                const float dot  = accE[r][c] + accO[r][c];   // even + odd
                const float dist = __fsub_rn(__fadd_rn(x2r[r], e4[c]),
                                             __fmul_rn(2.0f, dot));
                if (dist < best[r]) { best[r] = dist; bidx[r] = k0 + c; }
            }
        }
    }

    // cross-lane argmin over kg (butterfly); explicit lowest-index tie-break.
    #pragma unroll
    for (int off = 16; off <= 32; off <<= 1) {
        #pragma unroll
        for (int r = 0; r < 4; ++r) {
            const float ob = __shfl_down(best[r], off, 64);
            const int   oi = __shfl_down(bidx[r], off, 64);
            if (ob < best[r] || (ob == best[r] && oi < bidx[r])) {
                best[r] = ob; bidx[r] = oi;
            }
        }
    }
    if (kg == 0) {                    // lanes 0..15 hold the wave result
        #pragma unroll
        for (int r = 0; r < 4; ++r) {
            bestw[wv][rg * 4 + r] = best[r];
            bidxw[wv][rg * 4 + r] = bidx[r];
        }
    }
    __syncthreads();

    // cross-wave argmin; explicit lowest-index tie-break.
    if (t < RPB) {
        float bb = bestw[0][t];
        int   bi = bidxw[0][t];
        #pragma unroll
        for (int v = 1; v < NW; ++v) {
            const float c = bestw[v][t];
            const int   ci = bidxw[v][t];
            if (c < bb || (c == bb && ci < bi)) { bb = c; bi = ci; }
        }
        idxf[t] = bi;
    }
    __syncthreads();

    // ---- epilogue: q gather/store + loss. thread = (row rt, d-group dg).
    const int rt = t & 63;
    const int dg = t >> 6;            // 4 groups x 16 d
    const int widx = idxf[rt];
    const float* wrow = w + widx * DIM + dg * 16;
    const float* xrow = x + (size_t)b * DIM * HW + hw0 + rt;
    float* q = out + 1;
    float lsum = 0.0f;
    #pragma unroll
    for (int j = 0; j < 16; ++j) {
        const int d = dg * 16 + j;
        const float wvv = wrow[j];                    // per-lane gather, L1-hot
        const float xd  = xrow[(size_t)d * HW];
        const float df  = __fsub_rn(wvv, xd);
        lsum = __fadd_rn(lsum, __fmul_rn(df, df));
        q[(size_t)(b * DIM + d) * HW + hw0 + rt] = wvv;   // coalesced per d
    }

    #pragma unroll
    for (int off = 32; off; off >>= 1) lsum += __shfl_down(lsum, off, 64);
    if (lane == 0) lred[wv] = lsum;
    __syncthreads();
    if (t == 0) {
        float s = 0.0f;
        #pragma unroll
        for (int v = 0; v < NW; ++v) s += lred[v];
        partial[blockIdx.x] = s;
    }

    // ---- encodings: direct compute, aligned float4 middle
    // (slab global float index == 1 mod 4 -> peel 3, tail 1).
    float* slab = out + 1 + (size_t)NROWS * DIM + (size_t)n0 * KCODES;
    if (t < 3) slab[t] = (idxf[0] == t) ? 1.0f : 0.0f;
    if (t == 4) slab[RPB * KCODES - 1] = (idxf[RPB - 1] == 511) ? 1.0f : 0.0f;
    {
        v4f* s4 = (v4f*)(slab + 3);                   // 16B-aligned
        const int nf4 = (RPB * KCODES - 4) / 4;       // 8191
        for (int f = t; f < nf4; f += TPB) {
            const int ii = 3 + 4 * f;
            v4f o;
            #pragma unroll
            for (int c = 0; c < 4; ++c) {
                const int e = ii + c;
                o[c] = (idxf[e >> 9] == (e & 511)) ? 1.0f : 0.0f;
            }
            s4[f] = o;
        }
    }
}

__global__ __launch_bounds__(256) void vq_final(
    const float* __restrict__ partial, float* __restrict__ out)
{
    __shared__ float s[256];
    const int t = threadIdx.x;
    s[t] = (partial[t] + partial[t + 256]) + (partial[t + 512] + partial[t + 768]);
    __syncthreads();
    for (int off = 128; off; off >>= 1) {
        if (t < off) s[t] += s[t + off];
        __syncthreads();
    }
    if (t == 0) {
        const float m = s[0] / 4194304.0f;            // mean over B*H*W*D
        out[0] = __fadd_rn(m, __fmul_rn(0.25f, m));   // z_q + 0.25*z_e
    }
}

extern "C" void kernel_launch(void* const* d_in, const int* in_sizes, int n_in,
                              void* d_out, int out_size, void* d_ws, size_t ws_size,
                              hipStream_t stream) {
    const float* x = (const float*)d_in[0];
    const float* w = (const float*)d_in[1];
    float* out     = (float*)d_out;
    float* ws      = (float*)d_ws;

    vq_prep<<<258, 256, 0, stream>>>(x, w, ws);
    vq_main<<<NBLOCKS, TPB, 0, stream>>>(x, w, ws, out, ws + PART_OFF);
    vq_final<<<1, 256, 0, stream>>>(ws + PART_OFF, out);
}

// Round 7
// 234.242 us; speedup vs baseline: 1.9239x; 1.2051x over previous
//
#include <hip/hip_runtime.h>

// VQ-VAE forward: x [64,64,32,32] f32 (NCHW, C==D), weight [512,64] f32.
// d_out: loss (1) | q_out (4194304, NCHW) | encodings (33554432, [N,K]).
//
// R7: R6 was VMEM-instruction-issue bound (4.19M wave-loads x ~16cyc ~= 109us;
// broadcast lanes don't discount TA). Fixes:
//  - 8x8 per-lane tile (16 lane-FMA/load, 2x R6)
//  - x operand moved to LDS (staged once/block, E/O interleaved, 20-float
//    chunk pitch -> rg lanes hit distinct banks); w stays VMEM from
//    pre-interleaved wTp[dpair][k][2] -> two operand streams on two pipes
//  - v_pk_fma_f32 via v2f acc packing the (even,odd) chains; bitwise equal
//    to R6's accE/accO (dot = acc.x + acc.y).
// Tie order: within-lane k ascending + strict <; explicit lowest-index
// tie-break in all cross-lane/cross-wave merges (order-free => shfl_xor ok).

#define NROWS 65536
#define DIM 64
#define KCODES 512
#define HW 1024
#define TPB 256
#define RPB 64                      // rows per block
#define NBLOCKS (NROWS / RPB)       // 1024
#define NW 4

// d_ws float offsets
#define WT_OFF 0                    // wTp [32 dpair][512 k][2] = 32768 floats
#define E2_OFF 32768                // e2 [512]
#define X2_OFF 33280                // x2 [65536]
#define PART_OFF 98816              // partials [1024]

typedef float v2f __attribute__((ext_vector_type(2)));
typedef float v4f __attribute__((ext_vector_type(4)));

// xs layout: per dpair plane (32 planes): 8 chunks of 8 rows (v2f each);
// chunk pitch 20 floats (16 data + 4 pad): banks (c*20)%32 = 0,20,8,28,16,
// 4,24,12 -> all distinct; plane pitch 160 floats. Total 20480 B.
#define XS_IDX(dp, row) ((dp) * 160 + ((row) >> 3) * 20 + ((row) & 7) * 2)

__global__ __launch_bounds__(256) void vq_prep(
    const float* __restrict__ x, const float* __restrict__ w,
    float* __restrict__ ws)
{
    const int bid = blockIdx.x, t = threadIdx.x;
    if (bid < 2) {
        // w -> wTp[dpair][k][2] (E,O interleave) + e2 (ascending-d chain)
        const int k = bid * 256 + t;
        float s = 0.0f;
        for (int d = 0; d < DIM; ++d) {
            const float v = w[k * DIM + d];
            ws[WT_OFF + (d >> 1) * (KCODES * 2) + k * 2 + (d & 1)] = v;
            s = __fadd_rn(s, __fmul_rn(v, v));
        }
        ws[E2_OFF + k] = s;
    } else {
        // x2 per row, coalesced
        const int n = (bid - 2) * 256 + t;
        const int b = n >> 10, hw = n & 1023;
        const float* xr = x + (size_t)b * DIM * HW + hw;
        float s = 0.0f;
        for (int d = 0; d < DIM; ++d) {
            const float v = xr[(size_t)d * HW];
            s = __fadd_rn(s, __fmul_rn(v, v));
        }
        ws[X2_OFF + n] = s;
    }
}

__global__ __launch_bounds__(TPB, 2) void vq_main(
    const float* __restrict__ x, const float* __restrict__ w,
    const float* __restrict__ ws, float* __restrict__ out,
    float* __restrict__ partial)
{
    __shared__ __align__(16) float xs[32 * 160];   // 20480 B
    __shared__ float bestw[NW][RPB];
    __shared__ int   bidxw[NW][RPB];
    __shared__ int   idxf[RPB];
    __shared__ float lred[NW];

    const int t    = threadIdx.x;
    const int lane = t & 63;
    const int wv   = __builtin_amdgcn_readfirstlane(t >> 6);
    const int rg   = lane & 7;        // rows rg*8 .. rg*8+7
    const int kg   = lane >> 3;       // 8 codes per kit
    const int n0   = blockIdx.x * RPB;
    const int b    = n0 >> 10;        // no b straddle (1024 % 64 == 0)
    const int hw0  = n0 & 1023;

    // ---- stage x tile into LDS, (E,O) interleaved per dpair.
    {
        const int row4 = (t & 15) * 4;
        #pragma unroll
        for (int p = 0; p < 2; ++p) {
            const int dp = p * 16 + (t >> 4);
            const float* pe = x + (size_t)b * DIM * HW
                              + (size_t)(2 * dp) * HW + hw0 + row4;
            const v4f xe = *(const v4f*)pe;          // 4 rows, even depth
            const v4f xo = *(const v4f*)(pe + HW);   // 4 rows, odd depth
            const v4f o0 = {xe.x, xo.x, xe.y, xo.y};
            const v4f o1 = {xe.z, xo.z, xe.w, xo.w};
            float* dst = xs + XS_IDX(dp, row4);
            *(v4f*)dst       = o0;
            *(v4f*)(dst + 4) = o1;
        }
    }

    const v4f x2a = *(const v4f*)(ws + X2_OFF + n0 + rg * 8);
    const v4f x2b = *(const v4f*)(ws + X2_OFF + n0 + rg * 8 + 4);

    __syncthreads();

    const float* wT  = ws + WT_OFF;
    const float* e2p = ws + E2_OFF;

    float best[8];
    int   bidx[8];
    #pragma unroll
    for (int r = 0; r < 8; ++r) { best[r] = 3.4e38f; bidx[r] = 0; }

    const int xls = rg * 20;          // lane's float offset within a plane

    #pragma unroll 1
    for (int kit = 0; kit < 2; ++kit) {
        const int kb = wv * 128 + kit * 64 + kg * 8;   // lane's 8 codes
        v2f acc[8][8];
        #pragma unroll
        for (int r = 0; r < 8; ++r)
            #pragma unroll
            for (int c = 0; c < 8; ++c) acc[r][c] = (v2f){0.f, 0.f};

        const float* wp = wT + (size_t)kb * 2;
        const float* xp = xs + xls;
        #pragma unroll 4
        for (int dp = 0; dp < 32; ++dp) {
            const v4f X0 = *(const v4f*)(xp);        // rows 0,1 (E,O pairs)
            const v4f X1 = *(const v4f*)(xp + 4);    // rows 2,3
            const v4f X2 = *(const v4f*)(xp + 8);    // rows 4,5
            const v4f X3 = *(const v4f*)(xp + 12);   // rows 6,7
            const v4f W0 = *(const v4f*)(wp);        // codes 0,1
            const v4f W1 = *(const v4f*)(wp + 4);    // codes 2,3
            const v4f W2 = *(const v4f*)(wp + 8);    // codes 4,5
            const v4f W3 = *(const v4f*)(wp + 12);   // codes 6,7
            const v2f xr[8] = {X0.xy, X0.zw, X1.xy, X1.zw,
                               X2.xy, X2.zw, X3.xy, X3.zw};
            const v2f wc[8] = {W0.xy, W0.zw, W1.xy, W1.zw,
                               W2.xy, W2.zw, W3.xy, W3.zw};
            #pragma unroll
            for (int r = 0; r < 8; ++r)
                #pragma unroll
                for (int c = 0; c < 8; ++c)
                    acc[r][c] += xr[r] * wc[c];      // v_pk_fma_f32 (E,O)
            xp += 160;
            wp += KCODES * 2;
        }

        const v4f e20 = *(const v4f*)(e2p + kb);
        const v4f e21 = *(const v4f*)(e2p + kb + 4);
        #pragma unroll
        for (int r = 0; r < 8; ++r) {
            const float x2r = (r < 4) ? x2a[r] : x2b[r - 4];
            #pragma unroll
            for (int c = 0; c < 8; ++c) {            // c ascending: first-min
                const float dot  = acc[r][c][0] + acc[r][c][1];   // E + O
                const float e2c  = (c < 4) ? e20[c] : e21[c - 4];
                const float dist = __fsub_rn(__fadd_rn(x2r, e2c),
                                             __fmul_rn(2.0f, dot));
                if (dist < best[r]) { best[r] = dist; bidx[r] = kb + c; }
            }
        }
    }

    // ---- butterfly argmin over kg; explicit lowest-index tie-break.
    #pragma unroll
    for (int m = 8; m <= 32; m <<= 1) {
        #pragma unroll
        for (int r = 0; r < 8; ++r) {
            const float ob = __shfl_xor(best[r], m, 64);
            const int   oi = __shfl_xor(bidx[r], m, 64);
            if (ob < best[r] || (ob == best[r] && oi < bidx[r])) {
                best[r] = ob; bidx[r] = oi;
            }
        }
    }
    if (lane < 8) {                   // rg == lane: rows lane*8..+7
        #pragma unroll
        for (int r = 0; r < 8; ++r) {
            bestw[wv][lane * 8 + r] = best[r];
            bidxw[wv][lane * 8 + r] = bidx[r];
        }
    }
    __syncthreads();

    // ---- cross-wave argmin; explicit lowest-index tie-break.
    if (t < RPB) {
        float bb = bestw[0][t];
        int   bi = bidxw[0][t];
        #pragma unroll
        for (int v = 1; v < NW; ++v) {
            const float c  = bestw[v][t];
            const int   ci = bidxw[v][t];
            if (c < bb || (c == bb && ci < bi)) { bb = c; bi = ci; }
        }
        idxf[t] = bi;
    }
    __syncthreads();

    // ---- epilogue: q gather/store + loss. thread = (row rt, d-group dg).
    const int rt = t & 63;
    const int dg = t >> 6;            // 4 groups x 16 d
    const int widx = idxf[rt];
    const float* wrow = w + widx * DIM + dg * 16;
    const float* xrow = x + (size_t)b * DIM * HW + hw0 + rt;
    float* q = out + 1;
    float lsum = 0.0f;
    #pragma unroll
    for (int j = 0; j < 16; ++j) {
        const int d = dg * 16 + j;
        const float wvv = wrow[j];                    // per-lane gather, L1-hot
        const float xd  = xrow[(size_t)d * HW];
        const float df  = __fsub_rn(wvv, xd);
        lsum = __fadd_rn(lsum, __fmul_rn(df, df));
        q[(size_t)(b * DIM + d) * HW + hw0 + rt] = wvv;   // coalesced per d
    }

    #pragma unroll
    for (int off = 32; off; off >>= 1) lsum += __shfl_down(lsum, off, 64);
    if (lane == 0) lred[wv] = lsum;
    __syncthreads();
    if (t == 0) {
        float s = 0.0f;
        #pragma unroll
        for (int v = 0; v < NW; ++v) s += lred[v];
        partial[blockIdx.x] = s;
    }

    // ---- encodings: direct compute, aligned float4 middle
    // (slab global float index == 1 mod 4 -> peel 3, tail 1).
    float* slab = out + 1 + (size_t)NROWS * DIM + (size_t)n0 * KCODES;
    if (t < 3) slab[t] = (idxf[0] == t) ? 1.0f : 0.0f;
    if (t == 4) slab[RPB * KCODES - 1] = (idxf[RPB - 1] == 511) ? 1.0f : 0.0f;
    {
        v4f* s4 = (v4f*)(slab + 3);                   // 16B-aligned
        const int nf4 = (RPB * KCODES - 4) / 4;       // 8191
        for (int f = t; f < nf4; f += TPB) {
            const int ii = 3 + 4 * f;
            v4f o;
            #pragma unroll
            for (int c = 0; c < 4; ++c) {
                const int e = ii + c;
                o[c] = (idxf[e >> 9] == (e & 511)) ? 1.0f : 0.0f;
            }
            s4[f] = o;
        }
    }
}

__global__ __launch_bounds__(256) void vq_final(
    const float* __restrict__ partial, float* __restrict__ out)
{
    __shared__ float s[256];
    const int t = threadIdx.x;
    s[t] = (partial[t] + partial[t + 256]) + (partial[t + 512] + partial[t + 768]);
    __syncthreads();
    for (int off = 128; off; off >>= 1) {
        if (t < off) s[t] += s[t + off];
        __syncthreads();
    }
    if (t == 0) {
        const float m = s[0] / 4194304.0f;            // mean over B*H*W*D
        out[0] = __fadd_rn(m, __fmul_rn(0.25f, m));   // z_q + 0.25*z_e
    }
}

extern "C" void kernel_launch(void* const* d_in, const int* in_sizes, int n_in,
                              void* d_out, int out_size, void* d_ws, size_t ws_size,
                              hipStream_t stream) {
    const float* x = (const float*)d_in[0];
    const float* w = (const float*)d_in[1];
    float* out     = (float*)d_out;
    float* ws      = (float*)d_ws;

    vq_prep<<<258, 256, 0, stream>>>(x, w, ws);
    vq_main<<<NBLOCKS, TPB, 0, stream>>>(x, w, ws, out, ws + PART_OFF);
    vq_final<<<1, 256, 0, stream>>>(ws + PART_OFF, out);
}